// Round 2
// 14201.323 us; speedup vs baseline: 1.7606x; 1.7606x over previous
//
#include <hip/hip_runtime.h>
#include <math.h>

// Problem constants
#define S_ 64
#define B_ 32
#define T_ 64
#define E_ 512
#define H_ 1024
#define G_ 3072   // 3*H
#define V_ 32000

#define NBLK_ 256        // persistent grid size (== #CUs, 1 block/CU at our LDS use)
#define STG_STRIDE 72    // LDS row stride for staged h/ctx (72*4B: 2-way bank alias, 16B aligned)
#define STG_BUF (32 * STG_STRIDE)  // 2304 floats per stage buffer

__device__ __forceinline__ float sigmoidf_(float x) { return 1.f / (1.f + expf(-x)); }

// ---------------- manual grid barrier (persistent kernels, no cooperative API) --------
// One fresh zeroed counter per barrier instance. Thread 0: agent fence (wbL2) ->
// device-scope arrive -> relaxed spin -> acquire fence (invL1/L2). Deadman bound
// degrades to wrong-answer instead of hang if co-residency assumption breaks.
__device__ __forceinline__ void grid_barrier(unsigned int* bar, int id) {
  __syncthreads();
  if (threadIdx.x == 0) {
    __threadfence();
    __hip_atomic_fetch_add(&bar[id], 1u, __ATOMIC_RELEASE, __HIP_MEMORY_SCOPE_AGENT);
    int guard = 0;
    while (__hip_atomic_load(&bar[id], __ATOMIC_RELAXED, __HIP_MEMORY_SCOPE_AGENT) <
           gridDim.x) {
      __builtin_amdgcn_s_sleep(1);
      if (++guard > (1 << 17)) break;
    }
    __threadfence();
  }
  __syncthreads();
}

// ---------------- utility kernels ----------------
__global__ void zero_k(float* __restrict__ p, int n) {
  int i = blockIdx.x * blockDim.x + threadIdx.x;
  if (i < n) p[i] = 0.f;
}

__global__ void build_dec_idx_k(const int* __restrict__ tgt, int* __restrict__ idx) {
  int t = blockIdx.x, b = threadIdx.x;  // grid 64, block 32
  idx[t * B_ + b] = (t == 0) ? 2 : tgt[(t - 1) * B_ + b];
}

// ---------------- generic tiled fp32 GEMM: C = gather(A) @ W (+ bias) ----------------
template <bool GATHER, bool BIAS>
__global__ __launch_bounds__(256) void gemm_k(
    const float* __restrict__ A, const int* __restrict__ idx,
    const float* __restrict__ W, const float* __restrict__ bias,
    float* __restrict__ C, int M, int N, int K)
{
  __shared__ float As[16][64];
  __shared__ float Bs[16][64];
  const int n0 = blockIdx.x * 64;
  const int m0 = blockIdx.y * 64;
  const int tid = threadIdx.x;
  const int tx = tid & 15, ty = tid >> 4;
  float acc[4][4] = {};
  for (int k0 = 0; k0 < K; k0 += 16) {
    #pragma unroll
    for (int t = tid; t < 1024; t += 256) {
      int mm = t >> 4, kk = t & 15;
      int m = m0 + mm;
      const float* row = GATHER ? (A + (size_t)idx[m] * K) : (A + (size_t)m * K);
      As[kk][mm] = row[k0 + kk];
    }
    #pragma unroll
    for (int t = tid; t < 1024; t += 256) {
      int kk = t >> 6, nn = t & 63;
      Bs[kk][nn] = W[(size_t)(k0 + kk) * N + (n0 + nn)];
    }
    __syncthreads();
    #pragma unroll
    for (int kk = 0; kk < 16; ++kk) {
      float a[4], b[4];
      *(float4*)a = *(const float4*)&As[kk][ty * 4];
      *(float4*)b = *(const float4*)&Bs[kk][tx * 4];
      #pragma unroll
      for (int i = 0; i < 4; ++i)
        #pragma unroll
        for (int j = 0; j < 4; ++j)
          acc[i][j] = fmaf(a[i], b[j], acc[i][j]);
    }
    __syncthreads();
  }
  #pragma unroll
  for (int i = 0; i < 4; ++i) {
    int m = m0 + ty * 4 + i;
    float* crow = C + (size_t)m * N + n0;
    #pragma unroll
    for (int j = 0; j < 4; ++j) {
      int n = tx * 4 + j;
      crow[n] = acc[i][j] + (BIAS ? bias[n0 + n] : 0.f);
    }
  }
}

// ---------------- persistent-scan helpers ----------------
// Stage one 64-k chunk of a [32][1024] matrix into an LDS buffer [32][STG_STRIDE].
__device__ __forceinline__ void stage_issue(const float* __restrict__ src, int ck,
                                            float4* v, int tid) {
  #pragma unroll
  for (int r = 0; r < 2; ++r) {
    int q = tid + (r << 8);
    int row = q >> 4, c4 = q & 15;
    v[r] = *(const float4*)(src + (size_t)row * H_ + (ck << 6) + (c4 << 2));
  }
}
__device__ __forceinline__ void stage_write(float* __restrict__ buf, const float4* v,
                                            int tid) {
  #pragma unroll
  for (int r = 0; r < 2; ++r) {
    int q = tid + (r << 8);
    int row = q >> 4, c4 = q & 15;
    *(float4*)(buf + row * STG_STRIDE + (c4 << 2)) = v[r];
  }
}

#define LD8(dst, p)                                   \
  {                                                   \
    *(float4*)(dst) = *(const float4*)(p);            \
    *(float4*)((dst) + 4) = *(const float4*)((p) + 4);\
  }

// ---------------- persistent encoder scan (256 blocks x 256 thr, manual barrier) ----
// Block owns h-cols [i0, i0+4); Wh_e slice (12 gate cols x 1024 k) lives in LDS
// transposed [c][k] (stride 1032) for the whole 64-step scan.
__global__ __launch_bounds__(256, 1) void enc_scan_k(
    const float* __restrict__ Wh, const float* __restrict__ bh,
    const float* __restrict__ gx_all, const float* __restrict__ h0,
    float* __restrict__ enc_outs, unsigned int* __restrict__ bar)
{
  __shared__ __align__(16) float WT[12 * 1032];
  __shared__ __align__(16) float stg[2 * STG_BUF];
  __shared__ __align__(16) float red[8 * 512];
  const int tid = threadIdx.x;
  const int i0 = blockIdx.x * 4;

  // one-time weight transpose into LDS
  for (int q = tid; q < 3 * 1024; q += 256) {
    const int k = q & 1023, g = q >> 10;
    const float4 w = *(const float4*)(Wh + (size_t)k * G_ + g * H_ + i0);
    WT[(g * 4 + 0) * 1032 + k] = w.x;
    WT[(g * 4 + 1) * 1032 + k] = w.y;
    WT[(g * 4 + 2) * 1032 + k] = w.z;
    WT[(g * 4 + 3) * 1032 + k] = w.w;
  }
  float bhr = 0.f, bhz = 0.f, bhn = 0.f;
  if (tid < 128) {
    const int fi = i0 + (tid & 3);
    bhr = bh[fi]; bhz = bh[H_ + fi]; bhn = bh[2 * H_ + fi];
  }
  const int bg = tid & 7, il = (tid >> 3) & 3, ks = tid >> 5;
  __syncthreads();

  for (int s = 0; s < S_; ++s) {
    const float* hp = (s == 0) ? h0 : (enc_outs + (size_t)(s - 1) * B_ * H_);
    float4 v[2];
    stage_issue(hp, 0, v, tid);
    stage_write(stg, v, tid);
    __syncthreads();
    float ar[4] = {}, az[4] = {}, an[4] = {};
    for (int ck = 0; ck < 16; ++ck) {
      if (ck < 15) stage_issue(hp, ck + 1, v, tid);
      const float* buf = stg + (ck & 1) * STG_BUF;
      const int kb = ck * 64 + ks * 8;
      float wr[8], wz[8], wn[8];
      LD8(wr, WT + (0 + il) * 1032 + kb);
      LD8(wz, WT + (4 + il) * 1032 + kb);
      LD8(wn, WT + (8 + il) * 1032 + kb);
      #pragma unroll
      for (int u = 0; u < 4; ++u) {
        const float* hb = buf + (bg * 4 + u) * STG_STRIDE + ks * 8;
        float hh[8];
        LD8(hh, hb);
        #pragma unroll
        for (int k = 0; k < 8; ++k) {
          ar[u] = fmaf(hh[k], wr[k], ar[u]);
          az[u] = fmaf(hh[k], wz[k], az[u]);
          an[u] = fmaf(hh[k], wn[k], an[u]);
        }
      }
      if (ck < 15) stage_write(stg + ((ck + 1) & 1) * STG_BUF, v, tid);
      __syncthreads();
    }
    #pragma unroll
    for (int u = 0; u < 4; ++u)
      *(float4*)(red + ks * 512 + ((bg * 4 + u) * 4 + il) * 4) =
          make_float4(ar[u], az[u], an[u], 0.f);
    __syncthreads();
    if (tid < 128) {
      const int b = tid >> 2;
      const int fi = i0 + (tid & 3);
      float sar = 0.f, saz = 0.f, san = 0.f;
      #pragma unroll
      for (int k8 = 0; k8 < 8; ++k8) {
        const float4 p = *(const float4*)(red + k8 * 512 + tid * 4);
        sar += p.x; saz += p.y; san += p.z;
      }
      const float* gx = gx_all + ((size_t)s * B_ + b) * G_;
      const float r = sigmoidf_(gx[fi] + sar + bhr);
      const float z = sigmoidf_(gx[H_ + fi] + saz + bhz);
      const float n = tanhf(gx[2 * H_ + fi] + r * (san + bhn));
      enc_outs[((size_t)s * B_ + b) * H_ + fi] =
          (1.f - z) * n + z * hp[b * H_ + fi];
    }
    grid_barrier(bar, s);
  }
}

// ---------------- persistent decoder scan (256 blocks x 256 thr, manual barrier) ----
// LDS: WhT+WcT (12 gate cols each) + W1T (4 pre cols) resident for all 64 steps.
// Per step: A) pre=h@W1  B) scores  C) softmax+ctx  D) GRU gates. 4 barriers.
__global__ __launch_bounds__(256, 1) void dec_scan_k(
    const float* __restrict__ Wh, const float* __restrict__ Wc,
    const float* __restrict__ bh, const float* __restrict__ W1,
    const float* __restrict__ av, const float* __restrict__ gx_all,
    const float* __restrict__ enc_outs, const float* __restrict__ enc_proj,
    const float* __restrict__ h_init,
    float* __restrict__ pre_g, float* __restrict__ scr_g,
    float* __restrict__ ctx_g, float* __restrict__ dec_h,
    unsigned int* __restrict__ bar)
{
  __shared__ __align__(16) float WhT[12 * 1032];
  __shared__ __align__(16) float WcT[12 * 1032];
  __shared__ __align__(16) float W1T[4 * 1032];
  __shared__ __align__(16) float stg[4 * STG_BUF];
  __shared__ float awS[S_];
  float* red = stg;  // alias: reductions reuse stage area (phase-local, barrier-ordered)
  const int tid = threadIdx.x;
  const int i0 = blockIdx.x * 4;

  for (int q = tid; q < 3 * 1024; q += 256) {
    const int k = q & 1023, g = q >> 10;
    const float4 a = *(const float4*)(Wh + (size_t)k * G_ + g * H_ + i0);
    const float4 c = *(const float4*)(Wc + (size_t)k * G_ + g * H_ + i0);
    WhT[(g * 4 + 0) * 1032 + k] = a.x; WhT[(g * 4 + 1) * 1032 + k] = a.y;
    WhT[(g * 4 + 2) * 1032 + k] = a.z; WhT[(g * 4 + 3) * 1032 + k] = a.w;
    WcT[(g * 4 + 0) * 1032 + k] = c.x; WcT[(g * 4 + 1) * 1032 + k] = c.y;
    WcT[(g * 4 + 2) * 1032 + k] = c.z; WcT[(g * 4 + 3) * 1032 + k] = c.w;
  }
  for (int q = tid; q < 1024; q += 256) {
    const float4 w = *(const float4*)(W1 + (size_t)q * H_ + i0);
    W1T[0 * 1032 + q] = w.x; W1T[1 * 1032 + q] = w.y;
    W1T[2 * 1032 + q] = w.z; W1T[3 * 1032 + q] = w.w;
  }
  float bhr = 0.f, bhz = 0.f, bhn = 0.f;
  if (tid < 128) {
    const int fi = i0 + (tid & 3);
    bhr = bh[fi]; bhz = bh[H_ + fi]; bhn = bh[2 * H_ + fi];
  }
  const int bg = tid & 7, il = (tid >> 3) & 3, ks = tid >> 5;
  // phase B mapping: half-wave q = tid>>5 handles (bB, sB)
  const int sB = blockIdx.x >> 2;
  const int bB = (blockIdx.x & 3) * 8 + (tid >> 5);
  const int lB = tid & 31;
  // phase C mapping
  const int bC = blockIdx.x & 31, icC = blockIdx.x >> 5;
  __syncthreads();

  for (int t = 0; t < T_; ++t) {
    const float* hp = (t == 0) ? h_init : (dec_h + (size_t)(t - 1) * B_ * H_);

    // ---- A: pre = h @ W1 (block's 4 cols) ----
    {
      float4 v[2];
      stage_issue(hp, 0, v, tid);
      stage_write(stg, v, tid);
      __syncthreads();
      float pa[4] = {};
      for (int ck = 0; ck < 16; ++ck) {
        if (ck < 15) stage_issue(hp, ck + 1, v, tid);
        const float* buf = stg + (ck & 1) * STG_BUF;
        const int kb = ck * 64 + ks * 8;
        float w1r[8];
        LD8(w1r, W1T + il * 1032 + kb);
        #pragma unroll
        for (int u = 0; u < 4; ++u) {
          const float* hb = buf + (bg * 4 + u) * STG_STRIDE + ks * 8;
          float hh[8];
          LD8(hh, hb);
          #pragma unroll
          for (int k = 0; k < 8; ++k) pa[u] = fmaf(hh[k], w1r[k], pa[u]);
        }
        if (ck < 15) stage_write(stg + ((ck + 1) & 1) * STG_BUF, v, tid);
        __syncthreads();
      }
      #pragma unroll
      for (int u = 0; u < 4; ++u)
        red[ks * 128 + (bg * 4 + u) * 4 + il] = pa[u];
      __syncthreads();
      if (tid < 128) {
        float sp = 0.f;
        #pragma unroll
        for (int k8 = 0; k8 < 8; ++k8) sp += red[k8 * 128 + tid];
        pre_g[(tid >> 2) * H_ + i0 + (tid & 3)] = sp;
      }
    }
    grid_barrier(bar, 64 + t * 4 + 0);

    // ---- B: scores[b][s] = sum_k tanh(pre+enc_proj)*v ----
    {
      const float* pr = pre_g + (size_t)bB * H_;
      const float* ep = enc_proj + ((size_t)sB * B_ + bB) * H_;
      float acc = 0.f;
      #pragma unroll 4
      for (int kk = 0; kk < 32; ++kk) {
        const int k = lB + kk * 32;
        acc += tanhf(pr[k] + ep[k]) * av[k];
      }
      #pragma unroll
      for (int off = 16; off; off >>= 1) acc += __shfl_down(acc, off, 32);
      if (lB == 0) scr_g[bB * S_ + sB] = acc;
    }
    grid_barrier(bar, 64 + t * 4 + 1);

    // ---- C: softmax over s (redundant per 8 blocks of same b) + ctx slice ----
    if (tid < 64) {
      const float x = scr_g[bC * S_ + tid];
      float m = x;
      #pragma unroll
      for (int off = 32; off; off >>= 1) m = fmaxf(m, __shfl_xor(m, off));
      const float e = expf(x - m);
      float sum = e;
      #pragma unroll
      for (int off = 32; off; off >>= 1) sum += __shfl_xor(sum, off);
      awS[tid] = e / sum;
    }
    __syncthreads();
    {
      const int iloc = tid & 127, sh = tid >> 7;
      const int i = icC * 128 + iloc;
      float acc = 0.f;
      #pragma unroll 8
      for (int s2 = sh * 32; s2 < sh * 32 + 32; ++s2)
        acc = fmaf(awS[s2], enc_outs[((size_t)s2 * B_ + bC) * H_ + i], acc);
      red[sh * 128 + iloc] = acc;
    }
    __syncthreads();
    if (tid < 128)
      ctx_g[bC * H_ + icC * 128 + tid] = red[tid] + red[128 + tid];
    grid_barrier(bar, 64 + t * 4 + 2);

    // ---- D: gates = h@Wh + ctx@Wc -> GRU update ----
    {
      float4 vh[2], vc[2];
      stage_issue(hp, 0, vh, tid);
      stage_issue(ctx_g, 0, vc, tid);
      stage_write(stg, vh, tid);
      stage_write(stg + 2 * STG_BUF, vc, tid);
      __syncthreads();
      float ar[4] = {}, az[4] = {}, an[4] = {}, cn[4] = {};
      for (int ck = 0; ck < 16; ++ck) {
        if (ck < 15) {
          stage_issue(hp, ck + 1, vh, tid);
          stage_issue(ctx_g, ck + 1, vc, tid);
        }
        const float* bufh = stg + (ck & 1) * STG_BUF;
        const float* bufc = stg + 2 * STG_BUF + (ck & 1) * STG_BUF;
        const int kb = ck * 64 + ks * 8;
        float whr[8], whz[8], whn[8], wcr[8], wcz[8], wcn[8];
        LD8(whr, WhT + (0 + il) * 1032 + kb);
        LD8(whz, WhT + (4 + il) * 1032 + kb);
        LD8(whn, WhT + (8 + il) * 1032 + kb);
        LD8(wcr, WcT + (0 + il) * 1032 + kb);
        LD8(wcz, WcT + (4 + il) * 1032 + kb);
        LD8(wcn, WcT + (8 + il) * 1032 + kb);
        #pragma unroll
        for (int u = 0; u < 4; ++u) {
          const float* hb = bufh + (bg * 4 + u) * STG_STRIDE + ks * 8;
          const float* cb = bufc + (bg * 4 + u) * STG_STRIDE + ks * 8;
          float hh[8], cc[8];
          LD8(hh, hb);
          LD8(cc, cb);
          #pragma unroll
          for (int k = 0; k < 8; ++k) {
            ar[u] = fmaf(hh[k], whr[k], ar[u]);
            ar[u] = fmaf(cc[k], wcr[k], ar[u]);
            az[u] = fmaf(hh[k], whz[k], az[u]);
            az[u] = fmaf(cc[k], wcz[k], az[u]);
            an[u] = fmaf(hh[k], whn[k], an[u]);
            cn[u] = fmaf(cc[k], wcn[k], cn[u]);
          }
        }
        if (ck < 15) {
          stage_write(stg + ((ck + 1) & 1) * STG_BUF, vh, tid);
          stage_write(stg + 2 * STG_BUF + ((ck + 1) & 1) * STG_BUF, vc, tid);
        }
        __syncthreads();
      }
      #pragma unroll
      for (int u = 0; u < 4; ++u)
        *(float4*)(red + ks * 512 + ((bg * 4 + u) * 4 + il) * 4) =
            make_float4(ar[u], az[u], an[u], cn[u]);
      __syncthreads();
      if (tid < 128) {
        const int b = tid >> 2;
        const int fi = i0 + (tid & 3);
        float sar = 0.f, saz = 0.f, san = 0.f, scn = 0.f;
        #pragma unroll
        for (int k8 = 0; k8 < 8; ++k8) {
          const float4 p = *(const float4*)(red + k8 * 512 + tid * 4);
          sar += p.x; saz += p.y; san += p.z; scn += p.w;
        }
        const float* gx = gx_all + ((size_t)t * B_ + b) * G_;
        const float r = sigmoidf_(gx[fi] + sar + bhr);
        const float z = sigmoidf_(gx[H_ + fi] + saz + bhz);
        const float n = tanhf(gx[2 * H_ + fi] + scn + r * (san + bhn));
        dec_h[((size_t)t * B_ + b) * H_ + fi] =
            (1.f - z) * n + z * hp[b * H_ + fi];
      }
    }
    grid_barrier(bar, 64 + t * 4 + 3);
  }
}

// ---------------- log-softmax in place over rows of V ----------------
__global__ __launch_bounds__(256) void logsoftmax_k(float* __restrict__ out) {
  const int row = blockIdx.x;  // 2048 rows
  float* x = out + (size_t)row * V_;
  __shared__ float red[256];
  float m = -INFINITY;
  for (int v = threadIdx.x; v < V_; v += 256) m = fmaxf(m, x[v]);
  red[threadIdx.x] = m;
  __syncthreads();
  for (int s2 = 128; s2; s2 >>= 1) {
    if (threadIdx.x < s2) red[threadIdx.x] = fmaxf(red[threadIdx.x], red[threadIdx.x + s2]);
    __syncthreads();
  }
  m = red[0];
  __syncthreads();
  float sum = 0.f;
  for (int v = threadIdx.x; v < V_; v += 256) sum += expf(x[v] - m);
  red[threadIdx.x] = sum;
  __syncthreads();
  for (int s2 = 128; s2; s2 >>= 1) {
    if (threadIdx.x < s2) red[threadIdx.x] += red[threadIdx.x + s2];
    __syncthreads();
  }
  float lse = m + logf(red[0]);
  for (int v = threadIdx.x; v < V_; v += 256) x[v] -= lse;
}

extern "C" void kernel_launch(void* const* d_in, const int* in_sizes, int n_in,
                              void* d_out, int out_size, void* d_ws, size_t ws_size,
                              hipStream_t stream)
{
  const int*   src     = (const int*)  d_in[0];
  const int*   tgt     = (const int*)  d_in[1];
  const float* emb_enc = (const float*)d_in[2];
  const float* Wx_e    = (const float*)d_in[3];
  const float* Wh_e    = (const float*)d_in[4];
  const float* bx_e    = (const float*)d_in[5];
  const float* bh_e    = (const float*)d_in[6];
  const float* emb_dec = (const float*)d_in[7];
  const float* Wx_d    = (const float*)d_in[8];
  const float* Wh_d    = (const float*)d_in[9];
  const float* Wc_d    = (const float*)d_in[10];
  const float* bx_d    = (const float*)d_in[11];
  const float* bh_d    = (const float*)d_in[12];
  const float* attn_W  = (const float*)d_in[13];
  const float* attn_v  = (const float*)d_in[14];
  const float* Wout    = (const float*)d_in[15];
  const float* bout    = (const float*)d_in[16];
  float* out = (float*)d_out;

  // Workspace layout (~75.9 MB of fp32)
  float* ws       = (float*)d_ws;
  float* gx_enc   = ws;                          // 2048*3072
  float* gx_dec   = gx_enc  + 2048 * G_;         // 2048*3072
  float* enc_outs = gx_dec  + 2048 * G_;         // 64*32*1024
  float* enc_proj = enc_outs + 2048 * H_;        // 2048*1024
  float* dec_h    = enc_proj + 2048 * H_;        // 2048*1024
  float* h0       = dec_h   + 2048 * H_;         // 32*1024 (zeros)
  float* pre      = h0      + B_ * H_;           // 32*1024
  float* ctx      = pre     + B_ * H_;           // 32*1024
  int*   dec_idx  = (int*)(ctx + B_ * H_);       // 2048 ints
  unsigned int* bar = (unsigned int*)(dec_idx + 2048);  // 320 barrier counters
  float* scr      = gx_enc;                      // scores (32*64) reuse: dead after encoder

  // h0 = zeros; barrier counters = 0 (ws is poisoned 0xAA before every call)
  zero_k<<<dim3(32), dim3(1024), 0, stream>>>(h0, B_ * H_);
  zero_k<<<dim3(1), dim3(320), 0, stream>>>((float*)bar, 320);
  // decoder input ids: [SOS; tgt[:-1]]
  build_dec_idx_k<<<dim3(T_), dim3(B_), 0, stream>>>(tgt, dec_idx);

  // gx_enc = emb_enc[src] @ Wx_e + bx_e   (M=2048, N=3072, K=512)
  gemm_k<true, true><<<dim3(G_ / 64, 2048 / 64), 256, 0, stream>>>(
      emb_enc, src, Wx_e, bx_e, gx_enc, 2048, G_, E_);
  // gx_dec = emb_dec[dec_idx] @ Wx_d + bx_d
  gemm_k<true, true><<<dim3(G_ / 64, 2048 / 64), 256, 0, stream>>>(
      emb_dec, dec_idx, Wx_d, bx_d, gx_dec, 2048, G_, E_);

  // ---- encoder scan: one persistent kernel, manual grid barrier ----
  enc_scan_k<<<dim3(NBLK_), dim3(256), 0, stream>>>(
      Wh_e, bh_e, gx_enc, h0, enc_outs, bar);

  // enc_proj = enc_outs @ W2  (W2 = attn_W[H:])
  gemm_k<false, false><<<dim3(H_ / 64, 2048 / 64), 256, 0, stream>>>(
      enc_outs, nullptr, attn_W + (size_t)H_ * H_, nullptr, enc_proj, 2048, H_, H_);

  // ---- decoder scan: one persistent kernel, manual grid barrier ----
  dec_scan_k<<<dim3(NBLK_), dim3(256), 0, stream>>>(
      Wh_d, Wc_d, bh_d, attn_W, attn_v, gx_dec, enc_outs, enc_proj,
      enc_outs + (size_t)(S_ - 1) * B_ * H_, pre, scr, ctx, dec_h, bar);

  // logits = dec_h @ Wout + bout -> straight into d_out
  gemm_k<false, true><<<dim3(V_ / 64, 2048 / 64), 256, 0, stream>>>(
      dec_h, nullptr, Wout, bout, out, 2048, V_, H_);
  // log-softmax in place
  logsoftmax_k<<<dim3(2048), 256, 0, stream>>>(out);
}